// Round 8
// baseline (315.805 us; speedup 1.0000x reference)
//
#include <hip/hip_runtime.h>
#include <stdint.h>

typedef unsigned short u16;
typedef __attribute__((ext_vector_type(8))) short short8;
typedef __attribute__((ext_vector_type(4))) float f32x4;

#define KGU  5120
#define NPD  2560
#define KD   27648
#define SPLITD 12
#define KCHD 2304            // 27648/12
#define PEL (256*2560)

__device__ __forceinline__ uint32_t f2bf(float x) {
  uint32_t b = __float_as_uint(x);
  return (b + 0x7fffu + ((b >> 16) & 1u)) >> 16;
}
__device__ __forceinline__ uint32_t pk2(float lo, float hi) { return f2bf(lo) | (f2bf(hi) << 16); }
__device__ __forceinline__ uint32_t cvtpk(float lo, float hi) {
  uint32_t r;
  asm("v_cvt_pk_bf16_f32 %0, %1, %2" : "=v"(r) : "v"(lo), "v"(hi));
  return r;
}
__device__ __forceinline__ float silu(float x) {
  return x * __builtin_amdgcn_rcpf(1.f + __expf(-x));
}
#define MFMA16(a,b,c) __builtin_amdgcn_mfma_f32_16x16x32_bf16(a, b, c, 0, 0, 0)

// ---------------- kernel 0: x fp32 -> XF bf16, MFMA-fragment order ----------------
__global__ __launch_bounds__(256) void k_cvt(const float* __restrict__ X, u16* __restrict__ XF) {
  const int kt = blockIdx.x;
  const int lane = threadIdx.x & 63, wv = threadIdx.x >> 6;
#pragma unroll
  for (int ii = 0; ii < 4; ++ii) {
    const int mt = wv * 4 + ii;
    const float* src = X + (size_t)(mt * 16 + (lane & 15)) * KGU + kt * 32 + (lane >> 4) * 8;
    float4 f0 = *(const float4*)src;
    float4 f1 = *(const float4*)(src + 4);
    uint4 v;
    v.x = cvtpk(f0.x, f0.y); v.y = cvtpk(f0.z, f0.w);
    v.z = cvtpk(f1.x, f1.y); v.w = cvtpk(f1.z, f1.w);
    *(uint4*)(XF + ((size_t)(kt * 16 + mt) * 64 + lane) * 8) = v;
  }
}

// ---------------- kernel 1: gate+up GEMM, BM=256 x 64 cols (32 pairs), SK=64 ----------------
// 512 thr / 8 waves (4M x 2N), wave 64x32. Grid 432, XCD-chunked, 2 blocks/CU.
// A: loop-carried reg prefetch from XF (L2). B: dist-4 reg prefetch -> cvt once -> swizzled LDS.
// One s_barrier + lgkmcnt(0) per supertile; NO vmcnt(0) in loop (compiler counts exactly).
__global__ __launch_bounds__(512, 4)
void k_gu(const u16* __restrict__ XF,
          const float* __restrict__ Wg, const float* __restrict__ bg,
          const float* __restrict__ W1g, const float* __restrict__ b1g,
          const float* __restrict__ W2g, const float* __restrict__ b2g,
          const float* __restrict__ Wu, const float* __restrict__ bu,
          const float* __restrict__ W1u, const float* __restrict__ b1u,
          const float* __restrict__ W2u, const float* __restrict__ b2u,
          u16* __restrict__ HF) {
  __shared__ __align__(16) char smem[16384 + 1536];   // B dbuf 2x8KB + consts
  const int tid = threadIdx.x, lane = tid & 63, wid = tid >> 6;
  const int wm = wid >> 1, wn = wid & 1;
  const int s_ = lane & 15, quad = lane >> 4;
  const int bx = blockIdx.x;
  const int w = (bx & 7) * 54 + (bx >> 3);
  const int j0p = w * 32;

  float4* mc4 = (float4*)(smem + 16384);
  float*  mc1 = (float*)(smem + 16384 + 1024);
  if (tid < 64) {
    int sel = tid >> 5, m = tid & 31;
    const float* w1 = (sel ? W1u : W1g) + m * 6;
    const float* b1 = sel ? b1u : b1g;
    const float* w2 = sel ? W2u : W2g;
    mc4[sel * 32 + m] = make_float4(w1[0] + w1[2] + w1[4], w1[1] + w1[3] + w1[5], b1[m], w2[m]);
    mc1[sel * 32 + m] = w2[32 + m];
  }

  // B staging: lane -> LDS row r = 8*wid + (lane>>3) (even=gate, odd=up), k floats (lane&7)*8
  const int r_loc = 8 * wid + (lane >> 3);
  const float* srcB = ((r_loc & 1) ? Wu : Wg) + (size_t)(j0p + (r_loc >> 1)) * KGU + (lane & 7) * 8;
  const int bwr = r_loc * 128 + (((lane & 7) ^ (r_loc & 7)) << 4);
  // B-frag read rows
  const int rb = wn * 32 + s_;                 // ni=0 row; ni=1 -> +16 (same &7 class)
  const int rsw = s_ & 7;

  const short8* XFp = (const short8*)XF;
  const short8* paB = XFp + ((size_t)wm * 4) * 64 + lane;   // + (st*2+kk)*1024 + mi*64

  f32x4 acc[4][2];
#pragma unroll
  for (int i = 0; i < 4; ++i) { acc[i][0] = (f32x4)0.f; acc[i][1] = (f32x4)0.f; }
  float4 sr[4][2];
  short8 Ag[2][4];

  // prologue: B(0..3) regs, A(0) regs, B(0) -> LDS buf0
#pragma unroll
  for (int j = 0; j < 4; ++j) {
    sr[j][0] = *(const float4*)(srcB + j * 64);
    sr[j][1] = *(const float4*)(srcB + j * 64 + 4);
  }
#pragma unroll
  for (int kk = 0; kk < 2; ++kk)
#pragma unroll
    for (int mi = 0; mi < 4; ++mi) Ag[kk][mi] = paB[(size_t)kk * 1024 + mi * 64];
  {
    uint4 v;
    v.x = cvtpk(sr[0][0].x, sr[0][0].y); v.y = cvtpk(sr[0][0].z, sr[0][0].w);
    v.z = cvtpk(sr[0][1].x, sr[0][1].y); v.w = cvtpk(sr[0][1].z, sr[0][1].w);
    *(uint4*)(smem + bwr) = v;
  }
  asm volatile("s_waitcnt lgkmcnt(0)" ::: "memory");
  __builtin_amdgcn_sched_barrier(0);
  __builtin_amdgcn_s_barrier();

#pragma unroll 1
  for (int tb = 0; tb < 20; ++tb) {
#pragma unroll
    for (int j = 0; j < 4; ++j) {
      const int st = tb * 4 + j;
      const char* buf = smem + (j & 1) * 8192;
#pragma unroll
      for (int kk = 0; kk < 2; ++kk) {
        const int so = ((kk * 4 + quad) ^ rsw) << 4;
        short8 b0 = *(const short8*)(buf + rb * 128 + so);
        short8 b1 = *(const short8*)(buf + (rb + 16) * 128 + so);
        __builtin_amdgcn_s_setprio(1);
        acc[0][0] = MFMA16(Ag[kk][0], b0, acc[0][0]); acc[0][1] = MFMA16(Ag[kk][0], b1, acc[0][1]);
        acc[1][0] = MFMA16(Ag[kk][1], b0, acc[1][0]); acc[1][1] = MFMA16(Ag[kk][1], b1, acc[1][1]);
        acc[2][0] = MFMA16(Ag[kk][2], b0, acc[2][0]); acc[2][1] = MFMA16(Ag[kk][2], b1, acc[2][1]);
        acc[3][0] = MFMA16(Ag[kk][3], b0, acc[3][0]); acc[3][1] = MFMA16(Ag[kk][3], b1, acc[3][1]);
        __builtin_amdgcn_s_setprio(0);
        const int stn = (st < 79) ? st + 1 : 79;     // A(st+1) reload (issued before B refill)
        const short8* pa = paB + (size_t)(stn * 2 + kk) * 1024;
#pragma unroll
        for (int mi = 0; mi < 4; ++mi) Ag[kk][mi] = pa[mi * 64];
      }
      // stage B(st+1) -> other buf; refill that reg-set with B(st+5)
      const int jn = (j + 1) & 3;
      char* bufn = smem + (((j & 1) ^ 1)) * 8192;
      uint4 v;
      v.x = cvtpk(sr[jn][0].x, sr[jn][0].y); v.y = cvtpk(sr[jn][0].z, sr[jn][0].w);
      v.z = cvtpk(sr[jn][1].x, sr[jn][1].y); v.w = cvtpk(sr[jn][1].z, sr[jn][1].w);
      *(uint4*)(bufn + bwr) = v;
      const int stf = (st + 5 < 80) ? st + 5 : 79;
      sr[jn][0] = *(const float4*)(srcB + stf * 64);
      sr[jn][1] = *(const float4*)(srcB + stf * 64 + 4);
      asm volatile("s_waitcnt lgkmcnt(0)" ::: "memory");
      __builtin_amdgcn_sched_barrier(0);
      __builtin_amdgcn_s_barrier();
    }
  }

  // ---- fused epilogue: qrun per lane (gate even / up odd), shfl pair, silu*up -> HF frags ----
  const int sel = lane & 1;
  const float b2v0 = sel ? b2u[0] : b2g[0];
  const float b2v1 = sel ? b2u[1] : b2g[1];
  const float4* mcs = mc4 + sel * 32;
  const float*  mcw = mc1 + sel * 32;
  char* HFb = (char*)HF;
#pragma unroll
  for (int ni = 0; ni < 2; ++ni) {
    const int c = wn * 32 + ni * 16 + s_;
    const int j = j0p + (c >> 1);
    const float bp = sel ? bu[j] : bg[j];
#pragma unroll
    for (int mi = 0; mi < 4; ++mi) {
      float sv[4], cv[4], o0[4], o1[4];
#pragma unroll
      for (int e = 0; e < 4; ++e) {
        float p = acc[mi][ni][e] + bp;
        sv[e] = __sinf(p); cv[e] = __cosf(p);
        o0[e] = b2v0; o1[e] = b2v1;
      }
#pragma unroll 4
      for (int m = 0; m < 32; ++m) {
        float4 k4 = mcs[m]; float w2b = mcw[m];
#pragma unroll
        for (int e = 0; e < 4; ++e) {
          float hh = fmaxf(fmaf(sv[e], k4.x, fmaf(cv[e], k4.y, k4.z)), 0.f);
          o0[e] = fmaf(hh, k4.w, o0[e]);
          o1[e] = fmaf(hh, w2b, o1[e]);
        }
      }
#pragma unroll
      for (int e = 0; e < 4; ++e) {
        float t0 = __shfl_xor(o0[e], 1);
        float t1 = __shfl_xor(o1[e], 1);
        float g0 = sel ? t0 : o0[e];
        float u0 = sel ? o0[e] : t0;
        float g1 = sel ? t1 : o1[e];
        float u1 = sel ? o1[e] : t1;
        float h0 = silu(g0) * u0, h1 = silu(g1) * u1;
        if (!sel) {
          const int row = wm * 64 + mi * 16 + quad * 4 + e;
          const int kt2 = j >> 4, mt2 = wm * 4 + mi;
          const int lf2 = (row & 15) + 16 * ((j >> 2) & 3);
          *(uint32_t*)(HFb + (size_t)(kt2 * 16 + mt2) * 1024 + lf2 * 16 + (j & 3) * 4)
              = pk2(h0, h1);
        }
      }
    }
  }
}

// ---------------- kernel 2: down GEMM, BM=256 x BN=64, SK=64, splitK=12 ----------------
// Same pipeline. Grid 480 (8x60 XCD-chunked). A-frags from HF (L2 slice per sk).
__global__ __launch_bounds__(512, 4)
void k_down(const u16* __restrict__ HF, const float* __restrict__ Wd, float* __restrict__ P2) {
  __shared__ __align__(16) char smem[16384];
  const int tid = threadIdx.x, lane = tid & 63, wid = tid >> 6;
  const int wm = wid >> 1, wn = wid & 1;
  const int s_ = lane & 15, quad = lane >> 4;
  const int bx = blockIdx.x;
  const int w = (bx & 7) * 60 + (bx >> 3);
  const int sk = w / 40, nt = w - sk * 40;
  const int n0 = nt * 64;

  const int r_loc = 8 * wid + (lane >> 3);
  const float* srcB = Wd + (size_t)(n0 + r_loc) * KD + sk * KCHD + (lane & 7) * 8;
  const int bwr = r_loc * 128 + (((lane & 7) ^ (r_loc & 7)) << 4);
  const int rb = wn * 32 + s_;
  const int rsw = s_ & 7;

  const short8* HFp = (const short8*)HF;
  const short8* paB = HFp + ((size_t)(sk * 72) * 16 + wm * 4) * 64 + lane;

  f32x4 acc[4][2];
#pragma unroll
  for (int i = 0; i < 4; ++i) { acc[i][0] = (f32x4)0.f; acc[i][1] = (f32x4)0.f; }
  float4 sr[4][2];
  short8 Ag[2][4];

#pragma unroll
  for (int j = 0; j < 4; ++j) {
    sr[j][0] = *(const float4*)(srcB + j * 64);
    sr[j][1] = *(const float4*)(srcB + j * 64 + 4);
  }
#pragma unroll
  for (int kk = 0; kk < 2; ++kk)
#pragma unroll
    for (int mi = 0; mi < 4; ++mi) Ag[kk][mi] = paB[(size_t)kk * 1024 + mi * 64];
  {
    uint4 v;
    v.x = cvtpk(sr[0][0].x, sr[0][0].y); v.y = cvtpk(sr[0][0].z, sr[0][0].w);
    v.z = cvtpk(sr[0][1].x, sr[0][1].y); v.w = cvtpk(sr[0][1].z, sr[0][1].w);
    *(uint4*)(smem + bwr) = v;
  }
  asm volatile("s_waitcnt lgkmcnt(0)" ::: "memory");
  __builtin_amdgcn_sched_barrier(0);
  __builtin_amdgcn_s_barrier();

#pragma unroll 1
  for (int tb = 0; tb < 9; ++tb) {                  // 36 supertiles
#pragma unroll
    for (int j = 0; j < 4; ++j) {
      const int st = tb * 4 + j;
      const char* buf = smem + (j & 1) * 8192;
#pragma unroll
      for (int kk = 0; kk < 2; ++kk) {
        const int so = ((kk * 4 + quad) ^ rsw) << 4;
        short8 b0 = *(const short8*)(buf + rb * 128 + so);
        short8 b1 = *(const short8*)(buf + (rb + 16) * 128 + so);
        __builtin_amdgcn_s_setprio(1);
        acc[0][0] = MFMA16(Ag[kk][0], b0, acc[0][0]); acc[0][1] = MFMA16(Ag[kk][0], b1, acc[0][1]);
        acc[1][0] = MFMA16(Ag[kk][1], b0, acc[1][0]); acc[1][1] = MFMA16(Ag[kk][1], b1, acc[1][1]);
        acc[2][0] = MFMA16(Ag[kk][2], b0, acc[2][0]); acc[2][1] = MFMA16(Ag[kk][2], b1, acc[2][1]);
        acc[3][0] = MFMA16(Ag[kk][3], b0, acc[3][0]); acc[3][1] = MFMA16(Ag[kk][3], b1, acc[3][1]);
        __builtin_amdgcn_s_setprio(0);
        const int stn = (st < 35) ? st + 1 : 35;
        const short8* pa = paB + (size_t)(stn * 2 + kk) * 1024;
#pragma unroll
        for (int mi = 0; mi < 4; ++mi) Ag[kk][mi] = pa[mi * 64];
      }
      const int jn = (j + 1) & 3;
      char* bufn = smem + (((j & 1) ^ 1)) * 8192;
      uint4 v;
      v.x = cvtpk(sr[jn][0].x, sr[jn][0].y); v.y = cvtpk(sr[jn][0].z, sr[jn][0].w);
      v.z = cvtpk(sr[jn][1].x, sr[jn][1].y); v.w = cvtpk(sr[jn][1].z, sr[jn][1].w);
      *(uint4*)(bufn + bwr) = v;
      const int stf = (st + 5 < 36) ? st + 5 : 35;
      sr[jn][0] = *(const float4*)(srcB + stf * 64);
      sr[jn][1] = *(const float4*)(srcB + stf * 64 + 4);
      asm volatile("s_waitcnt lgkmcnt(0)" ::: "memory");
      __builtin_amdgcn_sched_barrier(0);
      __builtin_amdgcn_s_barrier();
    }
  }

  float* P = P2 + (size_t)sk * PEL;
#pragma unroll
  for (int mi = 0; mi < 4; ++mi) {
    int mrow = wm * 64 + mi * 16 + (quad << 2);
#pragma unroll
    for (int ni = 0; ni < 2; ++ni) {
      int n = n0 + wn * 32 + ni * 16 + s_;
#pragma unroll
      for (int e = 0; e < 4; ++e)
        P[(size_t)(mrow + e) * NPD + n] = acc[mi][ni][e];
    }
  }
}

// ---------------- kernel 3: reduce partials + QRUN-d epilogue -> out fp32 ----------------
__global__ __launch_bounds__(256) void k_fin(const float* __restrict__ P2, const float* __restrict__ bd,
    const float* __restrict__ W1d, const float* __restrict__ b1d, const float* __restrict__ W2d,
    const float* __restrict__ b2d, float* __restrict__ out) {
  __shared__ float4 mc0[32];
  __shared__ float mc1[32];
  const int tid = threadIdx.x;
  if (tid < 32) {
    const float* w = W1d + tid * 6;
    mc0[tid] = make_float4(w[0] + w[2] + w[4], w[1] + w[3] + w[5], b1d[tid], W2d[tid]);
    mc1[tid] = W2d[32 + tid];
  }
  __syncthreads();
  const int idx = blockIdx.x * 256 + tid;
  const int m = idx / NPD, j = idx - m * NPD;
  float p = bd[j];
#pragma unroll
  for (int sk = 0; sk < SPLITD; ++sk) p += P2[(size_t)sk * PEL + idx];
  float s = __sinf(p), c = __cosf(p);
  float o0 = b2d[0], o1 = b2d[1];
#pragma unroll 4
  for (int mm = 0; mm < 32; ++mm) {
    float4 k = mc0[mm];
    float hh = fmaxf(fmaf(s, k.x, fmaf(c, k.y, k.z)), 0.f);
    o0 = fmaf(hh, k.w, o0);
    o1 = fmaf(hh, mc1[mm], o1);
  }
  *(float2*)&out[(size_t)m * 5120 + 2 * j] = make_float2(o0, o1);
}

extern "C" void kernel_launch(void* const* d_in, const int* in_sizes, int n_in,
                              void* d_out, int out_size, void* d_ws, size_t ws_size,
                              hipStream_t stream) {
  const float* x   = (const float*)d_in[0];
  const float* Wg  = (const float*)d_in[1];
  const float* bg  = (const float*)d_in[2];
  const float* W1g = (const float*)d_in[3];
  const float* b1g = (const float*)d_in[4];
  const float* W2g = (const float*)d_in[5];
  const float* b2g = (const float*)d_in[6];
  const float* Wu  = (const float*)d_in[7];
  const float* bu  = (const float*)d_in[8];
  const float* W1u = (const float*)d_in[9];
  const float* b1u = (const float*)d_in[10];
  const float* W2u = (const float*)d_in[11];
  const float* b2u = (const float*)d_in[12];
  const float* Wd  = (const float*)d_in[13];
  const float* bd  = (const float*)d_in[14];
  const float* W1d = (const float*)d_in[15];
  const float* b1d = (const float*)d_in[16];
  const float* W2d = (const float*)d_in[17];
  const float* b2d = (const float*)d_in[18];
  char* ws = (char*)d_ws;
  u16*  XF = (u16*)ws;                     // 2,621,440 B
  u16*  HF = (u16*)(ws + 2621440);         // 14,155,776 B (ends 16,777,216)
  float* P2 = (float*)(ws + 16777216);     // 31,457,280 B
  if (ws_size < 48234496u) return;

  k_cvt<<<dim3(160), dim3(256), 0, stream>>>(x, XF);
  k_gu<<<dim3(432), dim3(512), 0, stream>>>(XF, Wg, bg, W1g, b1g, W2g, b2g,
                                            Wu, bu, W1u, b1u, W2u, b2u, HF);
  k_down<<<dim3(480), dim3(512), 0, stream>>>(HF, Wd, P2);
  k_fin<<<dim3(2560), dim3(256), 0, stream>>>(P2, bd, W1d, b1d, W2d, b2d, (float*)d_out);
}